// Round 5
// baseline (320.145 us; speedup 1.0000x reference)
//
#include <hip/hip_runtime.h>
#include <stdint.h>

#define NROWS 131072
#define BM 64
#define NK1 20
#define NK2 16
#define FSTR 1280
#define HSTR 1024

typedef __attribute__((ext_vector_type(8))) short bf16x8;
typedef __attribute__((ext_vector_type(4))) float f32x4;
typedef __attribute__((ext_vector_type(4))) int i32x4;
typedef __attribute__((ext_vector_type(2))) unsigned int u32x2;

__device__ __forceinline__ unsigned f2bf(float x) {
    union { float f; unsigned u; } v; v.f = x;
    unsigned r = v.u + 0x7FFFu + ((v.u >> 16) & 1u);
    return r >> 16;
}

// ws layout:
// [0, 655360)            W1 bf16 [512][640]
// [655360, 1179648)      W2 bf16 [512][512]
// [1179648, +2560)       wf[640] f32 (encode weights, cos folded to sin)
// [1182208, +2560)       bfv[640] f32 (encode biases, +pi/2 for cos)

__global__ void prep_kernel(
    const float* __restrict__ W1, const float* __restrict__ W2,
    const float* __restrict__ Wsx, const float* __restrict__ bsx,
    const float* __restrict__ Wcx, const float* __restrict__ bcx,
    const float* __restrict__ Wsy, const float* __restrict__ bsy,
    const float* __restrict__ Wcy, const float* __restrict__ bcy,
    const float* __restrict__ Wn, const float* __restrict__ bn,
    unsigned short* __restrict__ w1b, unsigned short* __restrict__ w2b,
    float* __restrict__ wf, float* __restrict__ bfv)
{
    int i = blockIdx.x * blockDim.x + threadIdx.x;
    const int n1 = 512 * 640;
    const int n2 = 512 * 512;
    if (i < n1) w1b[i] = (unsigned short)f2bf(W1[i]);
    else if (i < n1 + n2) w2b[i - n1] = (unsigned short)f2bf(W2[i - n1]);
    if (i < 640) {
        const float HPI = 1.57079632679489662f;
        float w, b;
        if (i < 512) {
            int j = i & 63, q = (i >> 6) & 3;
            if      (q == 0) { w = Wsx[j]; b = bsx[j]; }
            else if (q == 1) { w = Wcx[j]; b = bcx[j] + HPI; }
            else if (q == 2) { w = Wsy[j]; b = bsy[j]; }
            else             { w = Wcy[j]; b = bcy[j] + HPI; }
        } else { w = Wn[i - 512]; b = bn[i - 512]; }
        wf[i] = w; bfv[i] = b;
    }
}

// LDS: feats [64][640] bf16, stride 1280 B, byte-XOR ((row&7)<<4)  = 80 KB
//      h     [64][512] bf16, stride 1024 B, same XOR (aliased)

__global__ __launch_bounds__(512, 4) void mlp_kernel(
    const float* __restrict__ pf, const float* __restrict__ pt,
    const float* __restrict__ nm,
    const unsigned short* __restrict__ w1b,
    const unsigned short* __restrict__ w2b,
    const float* __restrict__ wf, const float* __restrict__ bfv,
    const float* __restrict__ b1, const float* __restrict__ b2,
    float* __restrict__ out)
{
    __shared__ __align__(16) unsigned char lds[81920];

    const int tid  = threadIdx.x;
    const int lane = tid & 63;
    const int wave = tid >> 6;          // 0..7, each owns 64 output cols
    const int l15  = lane & 15;
    const int l4   = lane >> 4;         // 0..3
    const int rowbase = blockIdx.x * BM;
    const int wcol = wave * 64;
    const unsigned swz = (unsigned)((l15 & 7) << 4);

    // A-operand (weights): row = out col (wcol+cf*16+l15), k = ks*32 + l4*8
    const unsigned short* w1p = w1b + (wcol + l15) * 640 + l4 * 8;
    const unsigned short* w2p = w2b + (wcol + l15) * 512 + l4 * 8;

    // depth-2 rotating W-fragment buffers (issued early, consumed 2 ks later)
    bf16x8 wbA[4], wbB[4];
    #pragma unroll
    for (int cf = 0; cf < 4; ++cf) {
        wbA[cf] = *(const bf16x8*)(w1p + cf * (16 * 640));
        wbB[cf] = *(const bf16x8*)(w1p + cf * (16 * 640) + 32);
    }

    // ---------------- encode: 8 threads/row, k = esub*8 + j*64 ----------------
    // Per j the 64-feature segment is uniform: j0,1->pf.x  j2,3->pf.y
    // j4,5->pt.x  j6,7->pt.y  j8,9->numbers ; sin for j<8 (cos folded in prep).
    {
        const int erow = tid >> 3;          // 0..63
        const int esub = tid & 7;
        const int grow = rowbase + erow;
        const float v0 = pf[grow * 2 + 0];
        const float v1 = pf[grow * 2 + 1];
        const float v2 = pt[grow * 2 + 0];
        const float v3 = pt[grow * 2 + 1];
        const float v4 = nm[grow];
        const unsigned eswz = (unsigned)((erow & 7) << 4);
        #pragma unroll
        for (int j = 0; j < 10; ++j) {
            const int k = esub * 8 + j * 64;
            const float xv = (j < 2) ? v0 : (j < 4) ? v1 :
                             (j < 6) ? v2 : (j < 8) ? v3 : v4;
            const f32x4 w0 = *(const f32x4*)(wf + k);
            const f32x4 w1v = *(const f32x4*)(wf + k + 4);
            const f32x4 c0 = *(const f32x4*)(bfv + k);
            const f32x4 c1 = *(const f32x4*)(bfv + k + 4);
            float r[8];
            #pragma unroll
            for (int t = 0; t < 4; ++t) {
                float a0 = fmaf(xv, w0[t], c0[t]);
                float a1 = fmaf(xv, w1v[t], c1[t]);
                if (j < 8) { r[t] = __sinf(a0); r[t + 4] = __sinf(a1); }
                else       { r[t] = a0;         r[t + 4] = a1; }
            }
            i32x4 pk;
            pk.x = (int)(f2bf(r[0]) | (f2bf(r[1]) << 16));
            pk.y = (int)(f2bf(r[2]) | (f2bf(r[3]) << 16));
            pk.z = (int)(f2bf(r[4]) | (f2bf(r[5]) << 16));
            pk.w = (int)(f2bf(r[6]) | (f2bf(r[7]) << 16));
            *(i32x4*)(lds + erow * FSTR + (((unsigned)(k * 2)) ^ eswz)) = pk;
        }
    }

    f32x4 acc[4][4];
    #pragma unroll
    for (int a = 0; a < 4; ++a)
        #pragma unroll
        for (int b = 0; b < 4; ++b) acc[a][b] = (f32x4)(0.0f);

    __syncthreads();

    // ---------------- layer 1: K=640, depth-2 reg-prefetch, no in-loop barriers ----
#define COMPUTE1(WB, KS) do {                                                      \
        _Pragma("unroll")                                                          \
        for (int rf = 0; rf < 4; ++rf) {                                           \
            bf16x8 af = *(const bf16x8*)(lds + (rf * 16 + l15) * FSTR +            \
                          (((unsigned)((KS) * 64 + l4 * 16)) ^ swz));              \
            _Pragma("unroll")                                                      \
            for (int cf = 0; cf < 4; ++cf)                                         \
                acc[rf][cf] = __builtin_amdgcn_mfma_f32_16x16x32_bf16(             \
                    WB[cf], af, acc[rf][cf], 0, 0, 0);                             \
        }                                                                          \
    } while (0)

    #pragma unroll
    for (int ks2 = 0; ks2 < 10; ++ks2) {
        const int ksA = 2 * ks2;
        COMPUTE1(wbA, ksA);
        if (ksA + 2 < NK1) {
            #pragma unroll
            for (int cf = 0; cf < 4; ++cf)
                wbA[cf] = *(const bf16x8*)(w1p + cf * (16 * 640) + (ksA + 2) * 32);
        }
        COMPUTE1(wbB, ksA + 1);
        if (ksA + 3 < NK1) {
            #pragma unroll
            for (int cf = 0; cf < 4; ++cf)
                wbB[cf] = *(const bf16x8*)(w1p + cf * (16 * 640) + (ksA + 3) * 32);
        }
    }

    // prologue W2 loads — latency hidden under h-epilogue + barrier
    #pragma unroll
    for (int cf = 0; cf < 4; ++cf) {
        wbA[cf] = *(const bf16x8*)(w2p + cf * (16 * 512));
        wbB[cf] = *(const bf16x8*)(w2p + cf * (16 * 512) + 32);
    }

    __syncthreads();   // all feats reads done; h may alias feats

    // ---------------- bias + leaky -> h (bf16, 8B LDS writes) ----------------
    #pragma unroll
    for (int cf = 0; cf < 4; ++cf) {
        const int colb = wcol + cf * 16 + l4 * 4;
        const f32x4 bb = *(const f32x4*)(b1 + colb);
        #pragma unroll
        for (int rf = 0; rf < 4; ++rf) {
            const int row = rf * 16 + l15;
            float h0 = acc[rf][cf][0] + bb[0];
            float h1 = acc[rf][cf][1] + bb[1];
            float h2 = acc[rf][cf][2] + bb[2];
            float h3 = acc[rf][cf][3] + bb[3];
            h0 = (h0 >= 0.f) ? h0 : 0.01f * h0;
            h1 = (h1 >= 0.f) ? h1 : 0.01f * h1;
            h2 = (h2 >= 0.f) ? h2 : 0.01f * h2;
            h3 = (h3 >= 0.f) ? h3 : 0.01f * h3;
            u32x2 pk;
            pk.x = f2bf(h0) | (f2bf(h1) << 16);
            pk.y = f2bf(h2) | (f2bf(h3) << 16);
            *(u32x2*)(lds + row * HSTR + (((unsigned)(colb * 2)) ^ swz)) = pk;
        }
    }

    #pragma unroll
    for (int a = 0; a < 4; ++a)
        #pragma unroll
        for (int b = 0; b < 4; ++b) acc[a][b] = (f32x4)(0.0f);

    __syncthreads();

    // ---------------- layer 2: K=512, same pipeline ----------------
#define COMPUTE2(WB, KS) do {                                                      \
        _Pragma("unroll")                                                          \
        for (int rf = 0; rf < 4; ++rf) {                                           \
            bf16x8 hf = *(const bf16x8*)(lds + (rf * 16 + l15) * HSTR +            \
                          (((unsigned)((KS) * 64 + l4 * 16)) ^ swz));              \
            _Pragma("unroll")                                                      \
            for (int cf = 0; cf < 4; ++cf)                                         \
                acc[rf][cf] = __builtin_amdgcn_mfma_f32_16x16x32_bf16(             \
                    WB[cf], hf, acc[rf][cf], 0, 0, 0);                             \
        }                                                                          \
    } while (0)

    #pragma unroll
    for (int ks2 = 0; ks2 < 8; ++ks2) {
        const int ksA = 2 * ks2;
        COMPUTE2(wbA, ksA);
        if (ksA + 2 < NK2) {
            #pragma unroll
            for (int cf = 0; cf < 4; ++cf)
                wbA[cf] = *(const bf16x8*)(w2p + cf * (16 * 512) + (ksA + 2) * 32);
        }
        COMPUTE2(wbB, ksA + 1);
        if (ksA + 3 < NK2) {
            #pragma unroll
            for (int cf = 0; cf < 4; ++cf)
                wbB[cf] = *(const bf16x8*)(w2p + cf * (16 * 512) + (ksA + 3) * 32);
        }
    }

    // ---------------- epilogue: bias + float4 stores ----------------
    #pragma unroll
    for (int cf = 0; cf < 4; ++cf) {
        const int colb = wcol + cf * 16 + l4 * 4;
        const f32x4 bb = *(const f32x4*)(b2 + colb);
        #pragma unroll
        for (int rf = 0; rf < 4; ++rf) {
            const int row = rowbase + rf * 16 + l15;
            f32x4 o = acc[rf][cf] + bb;
            *(f32x4*)(out + row * 512 + colb) = o;
        }
    }
}

extern "C" void kernel_launch(void* const* d_in, const int* in_sizes, int n_in,
                              void* d_out, int out_size, void* d_ws, size_t ws_size,
                              hipStream_t stream)
{
    (void)in_sizes; (void)n_in; (void)out_size; (void)ws_size;
    const float* pf  = (const float*)d_in[0];
    const float* pt  = (const float*)d_in[1];
    const float* nm  = (const float*)d_in[2];
    const float* Wsx = (const float*)d_in[3];
    const float* bsx = (const float*)d_in[4];
    const float* Wcx = (const float*)d_in[5];
    const float* bcx = (const float*)d_in[6];
    const float* Wsy = (const float*)d_in[7];
    const float* bsy = (const float*)d_in[8];
    const float* Wcy = (const float*)d_in[9];
    const float* bcy = (const float*)d_in[10];
    const float* Wn  = (const float*)d_in[11];
    const float* bn  = (const float*)d_in[12];
    const float* W1  = (const float*)d_in[13];
    const float* b1  = (const float*)d_in[14];
    const float* W2  = (const float*)d_in[15];
    const float* b2  = (const float*)d_in[16];

    unsigned char* ws = (unsigned char*)d_ws;
    unsigned short* w1b = (unsigned short*)(ws);
    unsigned short* w2b = (unsigned short*)(ws + 512 * 640 * 2);
    float* wf  = (float*)(ws + 512 * 640 * 2 + 512 * 512 * 2);
    float* bfv = (float*)(ws + 512 * 640 * 2 + 512 * 512 * 2 + 640 * 4);

    const int prep_threads = 512 * 640 + 512 * 512;
    prep_kernel<<<(prep_threads + 255) / 256, 256, 0, stream>>>(
        W1, W2, Wsx, bsx, Wcx, bcx, Wsy, bsy, Wcy, bcy, Wn, bn, w1b, w2b, wf, bfv);

    mlp_kernel<<<NROWS / BM, 512, 0, stream>>>(
        pf, pt, nm, w1b, w2b, wf, bfv, b1, b2, (float*)d_out);
}

// Round 6
// 195.950 us; speedup vs baseline: 1.6338x; 1.6338x over previous
//
#include <hip/hip_runtime.h>
#include <stdint.h>

#define NROWS 131072
#define BM 128
#define NK1 20
#define NK2 16
#define FSTR 1280
#define HSTR 1024

typedef __attribute__((ext_vector_type(8))) short bf16x8;
typedef __attribute__((ext_vector_type(4))) float f32x4;
typedef __attribute__((ext_vector_type(4))) int i32x4;
typedef __attribute__((ext_vector_type(2))) unsigned int u32x2;

__device__ __forceinline__ unsigned f2bf(float x) {
    union { float f; unsigned u; } v; v.f = x;
    unsigned r = v.u + 0x7FFFu + ((v.u >> 16) & 1u);
    return r >> 16;
}

// ws layout:
// [0, 655360)            W1 bf16 PACKED [wave8][ks20][cf4][lane64][8]
// [655360, 1179648)      W2 bf16 PACKED [wave8][ks16][cf4][lane64][8]
// [1179648, +2560)       wf[640] f32 (encode weights, cos folded to sin)
// [1182208, +2560)       bfv[640] f32 (encode biases, +pi/2 for cos)

__global__ void prep_kernel(
    const float* __restrict__ W1, const float* __restrict__ W2,
    const float* __restrict__ Wsx, const float* __restrict__ bsx,
    const float* __restrict__ Wcx, const float* __restrict__ bcx,
    const float* __restrict__ Wsy, const float* __restrict__ bsy,
    const float* __restrict__ Wcy, const float* __restrict__ bcy,
    const float* __restrict__ Wn, const float* __restrict__ bn,
    unsigned short* __restrict__ w1bp, unsigned short* __restrict__ w2bp,
    float* __restrict__ wf, float* __restrict__ bfv)
{
    int i = blockIdx.x * blockDim.x + threadIdx.x;
    const int n1 = 512 * 640;
    const int n2 = 512 * 512;
    if (i < n1) {
        // packed index -> (wave, ks, cf, lane, e) -> source W1[col][k]
        int e = i & 7, g = i >> 3;
        int lane = g & 63, cf = (g >> 6) & 3;
        int wk = g >> 8;                 // wave*20 + ks
        int ks = wk % 20, wv = wk / 20;
        int col = wv * 64 + cf * 16 + (lane & 15);
        int k   = ks * 32 + (lane >> 4) * 8 + e;
        w1bp[i] = (unsigned short)f2bf(W1[col * 640 + k]);
    } else if (i < n1 + n2) {
        int ii = i - n1;
        int e = ii & 7, g = ii >> 3;
        int lane = g & 63, cf = (g >> 6) & 3;
        int ks = (g >> 8) & 15, wv = g >> 12;
        int col = wv * 64 + cf * 16 + (lane & 15);
        int k   = ks * 32 + (lane >> 4) * 8 + e;
        w2bp[ii] = (unsigned short)f2bf(W2[col * 512 + k]);
    }
    if (i < 640) {
        const float HPI = 1.57079632679489662f;
        float w, b;
        if (i < 512) {
            int j = i & 63, q = (i >> 6) & 3;
            if      (q == 0) { w = Wsx[j]; b = bsx[j]; }
            else if (q == 1) { w = Wcx[j]; b = bcx[j] + HPI; }
            else if (q == 2) { w = Wsy[j]; b = bsy[j]; }
            else             { w = Wcy[j]; b = bcy[j] + HPI; }
        } else { w = Wn[i - 512]; b = bn[i - 512]; }
        wf[i] = w; bfv[i] = b;
    }
}

// LDS: feats [128][640] bf16, stride 1280 B, byte-XOR ((row&7)<<4) = 163840 B
//      h     [128][512] bf16, stride 1024 B, same XOR (aliased at base)

__global__ __launch_bounds__(512, 1) void mlp_kernel(
    const float* __restrict__ pf, const float* __restrict__ pt,
    const float* __restrict__ nm,
    const unsigned short* __restrict__ w1bp,
    const unsigned short* __restrict__ w2bp,
    const float* __restrict__ wf, const float* __restrict__ bfv,
    const float* __restrict__ b1, const float* __restrict__ b2,
    float* __restrict__ out)
{
    __shared__ __align__(16) unsigned char lds[163840];

    const int tid  = threadIdx.x;
    const int lane = tid & 63;
    const int wave = tid >> 6;          // 0..7, each owns 64 output cols
    const int l15  = lane & 15;
    const int l4   = lane >> 4;         // 0..3
    const int rowbase = blockIdx.x * BM;
    const int wcol = wave * 64;
    const unsigned swz = (unsigned)((l15 & 7) << 4);

    // PACKED W streams: per (ks,cf) one contiguous 1-KB fragment block.
    const unsigned short* w1p = w1bp + wave * (NK1 * 4 * 512) + lane * 8;
    const unsigned short* w2p = w2bp + wave * (NK2 * 4 * 512) + lane * 8;
#define W1FRAG(KS, CF) (*(const bf16x8*)(w1p + ((KS) * 4 + (CF)) * 512))
#define W2FRAG(KS, CF) (*(const bf16x8*)(w2p + ((KS) * 4 + (CF)) * 512))

    // depth-4 rotating register buffers for W fragments
    bf16x8 wb[4][4];
    #pragma unroll
    for (int t = 0; t < 4; ++t)
        #pragma unroll
        for (int cf = 0; cf < 4; ++cf)
            wb[t][cf] = W1FRAG(t, cf);

    // ---------------- encode: 4 threads/row, k = esub*8 + j*32 ----------------
    // Per j the 32-feature segment is uniform and compile-time:
    // j0-3 -> pf.x | j4-7 -> pf.y | j8-11 -> pt.x | j12-15 -> pt.y | j16-19 -> numbers
    // sin for j<16 (cos folded to sin in prep).
    {
        const int erow = tid >> 2;          // 0..127
        const int esub = tid & 3;
        const int grow = rowbase + erow;
        const float v0 = pf[grow * 2 + 0];
        const float v1 = pf[grow * 2 + 1];
        const float v2 = pt[grow * 2 + 0];
        const float v3 = pt[grow * 2 + 1];
        const float v4 = nm[grow];
        const unsigned eswz = (unsigned)((erow & 7) << 4);
        #pragma unroll
        for (int j = 0; j < 20; ++j) {
            const int k = esub * 8 + j * 32;
            const float xv = (j < 4) ? v0 : (j < 8) ? v1 :
                             (j < 12) ? v2 : (j < 16) ? v3 : v4;
            const f32x4 w0 = *(const f32x4*)(wf + k);
            const f32x4 w1v = *(const f32x4*)(wf + k + 4);
            const f32x4 c0 = *(const f32x4*)(bfv + k);
            const f32x4 c1 = *(const f32x4*)(bfv + k + 4);
            float r[8];
            #pragma unroll
            for (int t = 0; t < 4; ++t) {
                float a0 = fmaf(xv, w0[t], c0[t]);
                float a1 = fmaf(xv, w1v[t], c1[t]);
                if (j < 16) { r[t] = __sinf(a0); r[t + 4] = __sinf(a1); }
                else        { r[t] = a0;         r[t + 4] = a1; }
            }
            i32x4 pk;
            pk.x = (int)(f2bf(r[0]) | (f2bf(r[1]) << 16));
            pk.y = (int)(f2bf(r[2]) | (f2bf(r[3]) << 16));
            pk.z = (int)(f2bf(r[4]) | (f2bf(r[5]) << 16));
            pk.w = (int)(f2bf(r[6]) | (f2bf(r[7]) << 16));
            *(i32x4*)(lds + erow * FSTR + (((unsigned)(k * 2)) ^ eswz)) = pk;
        }
    }

    f32x4 acc[8][4];
    #pragma unroll
    for (int a = 0; a < 8; ++a)
        #pragma unroll
        for (int b = 0; b < 4; ++b) acc[a][b] = (f32x4)(0.0f);

    __syncthreads();

    // ---------------- layer 1: K=640, free-running depth-4 pipeline ----------------
    for (int ks2 = 0; ks2 < 5; ++ks2) {
        const int base = ks2 * 4;
        #pragma unroll
        for (int t = 0; t < 4; ++t) {
            const int ks = base + t;
            #pragma unroll
            for (int rf = 0; rf < 8; ++rf) {
                bf16x8 af = *(const bf16x8*)(lds + (rf * 16 + l15) * FSTR +
                              (((unsigned)(ks * 64 + l4 * 16)) ^ swz));
                #pragma unroll
                for (int cf = 0; cf < 4; ++cf)
                    acc[rf][cf] = __builtin_amdgcn_mfma_f32_16x16x32_bf16(
                        wb[t][cf], af, acc[rf][cf], 0, 0, 0);
            }
            if (ks + 4 < NK1) {
                #pragma unroll
                for (int cf = 0; cf < 4; ++cf)
                    wb[t][cf] = W1FRAG(ks + 4, cf);
            }
        }
    }

    // prologue W2 loads — latency hidden under h-epilogue + barrier
    #pragma unroll
    for (int t = 0; t < 4; ++t)
        #pragma unroll
        for (int cf = 0; cf < 4; ++cf)
            wb[t][cf] = W2FRAG(t, cf);

    __syncthreads();   // all feats reads done; h may alias feats

    // ---------------- bias + leaky -> h (bf16, 8B LDS writes) ----------------
    #pragma unroll
    for (int cf = 0; cf < 4; ++cf) {
        const int colb = wcol + cf * 16 + l4 * 4;
        const f32x4 bb = *(const f32x4*)(b1 + colb);
        #pragma unroll
        for (int rf = 0; rf < 8; ++rf) {
            const int row = rf * 16 + l15;
            float h0 = acc[rf][cf][0] + bb[0];
            float h1 = acc[rf][cf][1] + bb[1];
            float h2 = acc[rf][cf][2] + bb[2];
            float h3 = acc[rf][cf][3] + bb[3];
            h0 = (h0 >= 0.f) ? h0 : 0.01f * h0;
            h1 = (h1 >= 0.f) ? h1 : 0.01f * h1;
            h2 = (h2 >= 0.f) ? h2 : 0.01f * h2;
            h3 = (h3 >= 0.f) ? h3 : 0.01f * h3;
            u32x2 pk;
            pk.x = f2bf(h0) | (f2bf(h1) << 16);
            pk.y = f2bf(h2) | (f2bf(h3) << 16);
            *(u32x2*)(lds + row * HSTR + (((unsigned)(colb * 2)) ^ swz)) = pk;
        }
    }

    #pragma unroll
    for (int a = 0; a < 8; ++a)
        #pragma unroll
        for (int b = 0; b < 4; ++b) acc[a][b] = (f32x4)(0.0f);

    __syncthreads();

    // ---------------- layer 2: K=512, same pipeline ----------------
    for (int ks2 = 0; ks2 < 4; ++ks2) {
        const int base = ks2 * 4;
        #pragma unroll
        for (int t = 0; t < 4; ++t) {
            const int ks = base + t;
            #pragma unroll
            for (int rf = 0; rf < 8; ++rf) {
                bf16x8 hf = *(const bf16x8*)(lds + (rf * 16 + l15) * HSTR +
                              (((unsigned)(ks * 64 + l4 * 16)) ^ swz));
                #pragma unroll
                for (int cf = 0; cf < 4; ++cf)
                    acc[rf][cf] = __builtin_amdgcn_mfma_f32_16x16x32_bf16(
                        wb[t][cf], hf, acc[rf][cf], 0, 0, 0);
            }
            if (ks + 4 < NK2) {
                #pragma unroll
                for (int cf = 0; cf < 4; ++cf)
                    wb[t][cf] = W2FRAG(ks + 4, cf);
            }
        }
    }

    // ---------------- epilogue: bias + float4 stores ----------------
    #pragma unroll
    for (int cf = 0; cf < 4; ++cf) {
        const int colb = wcol + cf * 16 + l4 * 4;
        const f32x4 bb = *(const f32x4*)(b2 + colb);
        #pragma unroll
        for (int rf = 0; rf < 8; ++rf) {
            const int row = rowbase + rf * 16 + l15;
            f32x4 o = acc[rf][cf] + bb;
            *(f32x4*)(out + row * 512 + colb) = o;
        }
    }
}

extern "C" void kernel_launch(void* const* d_in, const int* in_sizes, int n_in,
                              void* d_out, int out_size, void* d_ws, size_t ws_size,
                              hipStream_t stream)
{
    (void)in_sizes; (void)n_in; (void)out_size; (void)ws_size;
    const float* pf  = (const float*)d_in[0];
    const float* pt  = (const float*)d_in[1];
    const float* nm  = (const float*)d_in[2];
    const float* Wsx = (const float*)d_in[3];
    const float* bsx = (const float*)d_in[4];
    const float* Wcx = (const float*)d_in[5];
    const float* bcx = (const float*)d_in[6];
    const float* Wsy = (const float*)d_in[7];
    const float* bsy = (const float*)d_in[8];
    const float* Wcy = (const float*)d_in[9];
    const float* bcy = (const float*)d_in[10];
    const float* Wn  = (const float*)d_in[11];
    const float* bn  = (const float*)d_in[12];
    const float* W1  = (const float*)d_in[13];
    const float* b1  = (const float*)d_in[14];
    const float* W2  = (const float*)d_in[15];
    const float* b2  = (const float*)d_in[16];

    unsigned char* ws = (unsigned char*)d_ws;
    unsigned short* w1bp = (unsigned short*)(ws);
    unsigned short* w2bp = (unsigned short*)(ws + 512 * 640 * 2);
    float* wf  = (float*)(ws + 512 * 640 * 2 + 512 * 512 * 2);
    float* bfv = (float*)(ws + 512 * 640 * 2 + 512 * 512 * 2 + 640 * 4);

    const int prep_threads = 512 * 640 + 512 * 512;
    prep_kernel<<<(prep_threads + 255) / 256, 256, 0, stream>>>(
        W1, W2, Wsx, bsx, Wcx, bcx, Wsy, bsy, Wcy, bcy, Wn, bn, w1bp, w2bp, wf, bfv);

    mlp_kernel<<<NROWS / BM, 512, 0, stream>>>(
        pf, pt, nm, w1bp, w2bp, wf, bfv, b1, b2, (float*)d_out);
}